// Round 3
// baseline (840.575 us; speedup 1.0000x reference)
//
#include <hip/hip_runtime.h>

// RGAT encoder, 2 layers. N=32768, E=160000, DIM=768, R=3, heads 4 then 1.
// Round 3 (from 828.5 us / absmax 0.0078):
//  - GEMM grid swizzle: blockIdx.x = (bn,r) [18], y = bm [256] so co-resident
//    blocks share A-tiles -> A fetched ~once (FETCH 320MB -> ~90MB predicted)
//  - qnkn: float4 weight loads over h (was 24 scalar dword loads per j-step,
//    VMEM-issue bound) + float4 stores
//  - agg: float4 qn/kn loads (H=4) + 1-deep software prefetch of next edge's
//    xr row and weight (hides one LLC gather latency per edge)
// Inputs are fp32 on device (detected round 2); detection retained for safety.

#define DIM   768
#define NREL  3

typedef __bf16 bf16x8 __attribute__((ext_vector_type(8)));
typedef float  f32x4  __attribute__((ext_vector_type(4)));
typedef unsigned short us4 __attribute__((ext_vector_type(4)));

// ---------------- helpers ----------------
__device__ __forceinline__ float bfs(unsigned short u){
  union { unsigned u; float f; } v; v.u = ((unsigned)u) << 16; return v.f;
}
__device__ __forceinline__ float bfl(unsigned x){
  union { unsigned u; float f; } v; v.u = x << 16; return v.f;
}
__device__ __forceinline__ float bfh(unsigned x){
  union { unsigned u; float f; } v; v.u = x & 0xffff0000u; return v.f;
}
__device__ __forceinline__ unsigned short f2bf(float f){   // RNE
  union { float f; unsigned u; } v; v.f = f;
  unsigned r = v.u + 0x7fffu + ((v.u >> 16) & 1u);
  return (unsigned short)(r >> 16);
}
__device__ __forceinline__ unsigned pck(float a, float b){
  return (unsigned)f2bf(a) | ((unsigned)f2bf(b) << 16);
}
__device__ __forceinline__ float ldf(const void* p, size_t i, int is32){
  return is32 ? ((const float*)p)[i] : bfs(((const unsigned short*)p)[i]);
}
__device__ __forceinline__ int ldi(const void* p, size_t i, int is64){
  return is64 ? ((const int*)p)[2 * i] : ((const int*)p)[i];
}

typedef __attribute__((address_space(1))) void gvoid_t;
typedef __attribute__((address_space(3))) void lvoid_t;
__device__ __forceinline__ void gload16(const void* g, void* l){
  __builtin_amdgcn_global_load_lds((gvoid_t*)g, (lvoid_t*)l, 16, 0, 0);
}

template<int H>
__device__ __forceinline__ float sel(const float (&a)[H], int h){
  float v = a[0];
#pragma unroll
  for (int i = 1; i < H; ++i) v = (h == i) ? a[i] : v;
  return v;
}

// ---------------- dtype detection ----------------
__global__ void detect_kernel(const unsigned short* __restrict__ xu,
                              const unsigned* __restrict__ eiu,
                              const unsigned* __restrict__ etyu,
                              int* __restrict__ flags){
  __shared__ int s_weird, s_ei, s_ety;
  int t = threadIdx.x;
  if (t == 0){ s_weird = 0; s_ei = 0; s_ety = 0; }
  __syncthreads();
  unsigned short u = xu[2 * t];
  int ex = (u >> 7) & 0xff;
  if (ex >= 0xF0 || ex <= 0x40) atomicAdd(&s_weird, 1);
  if (t < 128){
    if (eiu[2 * t + 1]  != 0) atomicAdd(&s_ei, 1);
    if (etyu[2 * t + 1] != 0) atomicAdd(&s_ety, 1);
  }
  __syncthreads();
  if (t == 0){
    flags[0] = (s_weird > 16) ? 1 : 0;
    flags[1] = (s_ei  == 0) ? 1 : 0;
    flags[2] = (s_ety == 0) ? 1 : 0;
  }
}

// ---------------- x -> internal bf16 ----------------
__global__ void convert_x(const void* __restrict__ xin, unsigned short* __restrict__ xb,
                          const int* __restrict__ flags, int n4){
  int i = blockIdx.x * blockDim.x + threadIdx.x;
  if (i >= n4) return;
  if (flags[0]){
    float4 v = ((const float4*)xin)[i];
    us4 o; o.x = f2bf(v.x); o.y = f2bf(v.y); o.z = f2bf(v.z); o.w = f2bf(v.w);
    ((us4*)xb)[i] = o;
  } else {
    ((us4*)xb)[i] = ((const us4*)xin)[i];
  }
}

// ---------------- CSR build ----------------
__global__ void hist_kernel(const void* __restrict__ ei, int* __restrict__ counts,
                            const int* __restrict__ flags, int E){
  int e = blockIdx.x * blockDim.x + threadIdx.x;
  if (e < E) atomicAdd(&counts[ldi(ei, (size_t)E + e, flags[1])], 1);
}

__global__ void scan_kernel(const int* __restrict__ counts, int* __restrict__ offs,
                            int* __restrict__ cursor, int n){
  __shared__ int s[1024];
  int tid = threadIdx.x;
  int base = tid * 32;
  int loc[32];
  int run = 0;
#pragma unroll
  for (int i = 0; i < 32; ++i){ loc[i] = run; run += counts[base + i]; }
  s[tid] = run;
  __syncthreads();
  for (int off = 1; off < 1024; off <<= 1){
    int add = (tid >= off) ? s[tid - off] : 0;
    __syncthreads();
    s[tid] += add;
    __syncthreads();
  }
  int ex = (tid == 0) ? 0 : s[tid - 1];
#pragma unroll
  for (int i = 0; i < 32; ++i){
    int o = ex + loc[i];
    offs[base + i]   = o;
    cursor[base + i] = o;
  }
  if (tid == 1023) offs[n] = s[1023];
}

__global__ void scatter_kernel(const void* __restrict__ ei, const void* __restrict__ ety,
                               int* __restrict__ cursor, int* __restrict__ payload,
                               const int* __restrict__ flags, int E){
  int e = blockIdx.x * blockDim.x + threadIdx.x;
  if (e < E){
    int dst = ldi(ei, (size_t)E + e, flags[1]);
    int src = ldi(ei, (size_t)e,     flags[1]);
    int et  = ldi(ety, (size_t)e,    flags[2]);
    int pos = atomicAdd(&cursor[dst], 1);
    payload[pos] = (et << 16) | src;
  }
}

// ---------------- W transpose+convert ----------------
__global__ void transpose_w(const void* __restrict__ W, unsigned short* __restrict__ Wt,
                            const int* __restrict__ flags){
  __shared__ unsigned short t[32][33];
  int is32 = flags[0];
  int r = blockIdx.z;
  size_t Wb = (size_t)r * DIM * DIM;
  unsigned short* Wd = Wt + (size_t)r * DIM * DIM;
  int tx = threadIdx.x, ty = threadIdx.y;
  int x  = blockIdx.x * 32 + tx;
  int y0 = blockIdx.y * 32;
#pragma unroll
  for (int i = 0; i < 32; i += 8)
    t[ty + i][tx] = f2bf(ldf(W, Wb + (size_t)(y0 + ty + i) * DIM + x, is32));
  __syncthreads();
  int x2 = blockIdx.y * 32 + tx;
  int y2 = blockIdx.x * 32;
#pragma unroll
  for (int i = 0; i < 32; i += 8) Wd[(size_t)(y2 + ty + i) * DIM + x2] = t[tx][ty + i];
}

// ---------------- Wq[r][d][h] = sum_f W[r][d][f]*q[f][h] ----------------
template<int H>
__global__ void wqk_kernel(const void* __restrict__ W,
                           const void* __restrict__ q, const void* __restrict__ k,
                           float* __restrict__ Wq, float* __restrict__ Wk,
                           const int* __restrict__ flags){
  int is32 = flags[0];
  int wid  = (blockIdx.x * blockDim.x + threadIdx.x) >> 6;
  int lane = threadIdx.x & 63;
  int r = wid / DIM, d = wid % DIM;
  size_t Wrow = ((size_t)r * DIM + d) * DIM;
  float aq[H], ak[H];
#pragma unroll
  for (int h = 0; h < H; ++h){ aq[h] = 0.f; ak[h] = 0.f; }
#pragma unroll
  for (int j = 0; j < 12; ++j){
    int f = j * 64 + lane;
    float wv = ldf(W, Wrow + f, is32);
#pragma unroll
    for (int h = 0; h < H; ++h){
      aq[h] += wv * ldf(q, (size_t)f * H + h, is32);
      ak[h] += wv * ldf(k, (size_t)f * H + h, is32);
    }
  }
#pragma unroll
  for (int h = 0; h < H; ++h){
    for (int off = 32; off; off >>= 1){
      aq[h] += __shfl_xor(aq[h], off);
      ak[h] += __shfl_xor(ak[h], off);
    }
  }
  if (lane == 0){
#pragma unroll
    for (int h = 0; h < H; ++h){
      Wq[((size_t)r * DIM + d) * H + h] = aq[h];
      Wk[((size_t)r * DIM + d) * H + h] = ak[h];
    }
  }
}

// ---------------- qn[r][n][h] = X[n] @ Wq[r]  (X internal bf16) ----------------
template<int H>
__global__ void qnkn_kernel(const unsigned short* __restrict__ X,
                            const float* __restrict__ Wq, const float* __restrict__ Wk,
                            float* __restrict__ qn, float* __restrict__ kn, int nN){
  int wid  = (blockIdx.x * blockDim.x + threadIdx.x) >> 6;
  int lane = threadIdx.x & 63;
  const unsigned short* xrow = X + (size_t)wid * DIM;
  float aq[NREL][H], ak[NREL][H];
#pragma unroll
  for (int r = 0; r < NREL; ++r)
#pragma unroll
    for (int h = 0; h < H; ++h){ aq[r][h] = 0.f; ak[r][h] = 0.f; }
#pragma unroll
  for (int j = 0; j < 12; ++j){
    int d = j * 64 + lane;
    float xv = bfs(xrow[d]);
    if (H == 4){
      const f32x4* Wq4 = (const f32x4*)Wq;
      const f32x4* Wk4 = (const f32x4*)Wk;
#pragma unroll
      for (int r = 0; r < NREL; ++r){
        f32x4 a = Wq4[(size_t)r * DIM + d];
        f32x4 b = Wk4[(size_t)r * DIM + d];
#pragma unroll
        for (int h = 0; h < H; ++h){
          aq[r][h] += xv * a[h & 3];
          ak[r][h] += xv * b[h & 3];
        }
      }
    } else {
#pragma unroll
      for (int r = 0; r < NREL; ++r){
        aq[r][0] += xv * Wq[(size_t)r * DIM + d];
        ak[r][0] += xv * Wk[(size_t)r * DIM + d];
      }
    }
  }
#pragma unroll
  for (int r = 0; r < NREL; ++r)
#pragma unroll
    for (int h = 0; h < H; ++h){
      for (int off = 32; off; off >>= 1){
        aq[r][h] += __shfl_xor(aq[r][h], off);
        ak[r][h] += __shfl_xor(ak[r][h], off);
      }
    }
  if (lane == 0){
    if (H == 4){
#pragma unroll
      for (int r = 0; r < NREL; ++r){
        f32x4 vq, vk;
#pragma unroll
        for (int h = 0; h < H; ++h){ vq[h & 3] = aq[r][h]; vk[h & 3] = ak[r][h]; }
        *(f32x4*)(qn + ((size_t)r * nN + wid) * H) = vq;
        *(f32x4*)(kn + ((size_t)r * nN + wid) * H) = vk;
      }
    } else {
#pragma unroll
      for (int r = 0; r < NREL; ++r){
        qn[(size_t)r * nN + wid] = aq[r][0];
        kn[(size_t)r * nN + wid] = ak[r][0];
      }
    }
  }
}

// ---------------- MFMA GEMM: C[r] = A @ W[r] ----------------
// grid: x = bn + (DIM/128)*r  (18), y = bm (256) -> co-resident blocks share A
__global__ void __launch_bounds__(256)
gemm_bf16(const unsigned short* __restrict__ A,
          const unsigned short* __restrict__ Bt,
          unsigned short* __restrict__ C, int M){
  __shared__ __align__(16) unsigned char lA[128 * 64 * 2];
  __shared__ __align__(16) unsigned char lB[128 * 64 * 2];
  const int K = DIM;
  const int NBN = DIM / 128;
  int bn = blockIdx.x % NBN, r = blockIdx.x / NBN;
  int bm = blockIdx.y;
  int tid = threadIdx.x;
  int w = tid >> 6, lane = tid & 63;
  int wr = w >> 1, wc = w & 1;
  int q = lane >> 4, m16 = lane & 15;
  int sr8 = lane >> 3, kc = lane & 7;

  const unsigned short* Ag = A  + (size_t)bm * 128 * K;
  const unsigned short* Bg = Bt + ((size_t)r * DIM + (size_t)bn * 128) * K;

  f32x4 acc[4][4];
#pragma unroll
  for (int i = 0; i < 4; ++i)
#pragma unroll
    for (int j = 0; j < 4; ++j) acc[i][j] = (f32x4){0.f, 0.f, 0.f, 0.f};

  for (int k0 = 0; k0 < K; k0 += 64){
#pragma unroll
    for (int it = 0; it < 4; ++it){
      int row = w * 32 + it * 8 + sr8;
      int cl  = kc ^ (row & 7);
      gload16(Ag + (size_t)row * K + k0 + cl * 8, &lA[(w * 32 + it * 8) * 128]);
      gload16(Bg + (size_t)row * K + k0 + cl * 8, &lB[(w * 32 + it * 8) * 128]);
    }
    __builtin_amdgcn_s_waitcnt(0);
    __syncthreads();
#pragma unroll
    for (int kk = 0; kk < 2; ++kk){
      bf16x8 af[4], bfr[4];
      int c = kk * 4 + q;
#pragma unroll
      for (int mi = 0; mi < 4; ++mi){
        int row = wr * 64 + mi * 16 + m16;
        af[mi] = *(const bf16x8*)&lA[row * 128 + ((c ^ (row & 7)) << 4)];
      }
#pragma unroll
      for (int ni = 0; ni < 4; ++ni){
        int row = wc * 64 + ni * 16 + m16;
        bfr[ni] = *(const bf16x8*)&lB[row * 128 + ((c ^ (row & 7)) << 4)];
      }
#pragma unroll
      for (int mi = 0; mi < 4; ++mi)
#pragma unroll
        for (int ni = 0; ni < 4; ++ni)
          acc[mi][ni] = __builtin_amdgcn_mfma_f32_16x16x32_bf16(af[mi], bfr[ni], acc[mi][ni], 0, 0, 0);
    }
    __syncthreads();
  }
  unsigned short* Cg = C + ((size_t)r * M + (size_t)bm * 128) * DIM + bn * 128;
#pragma unroll
  for (int mi = 0; mi < 4; ++mi)
#pragma unroll
    for (int ni = 0; ni < 4; ++ni){
#pragma unroll
      for (int j = 0; j < 4; ++j){
        int row = wr * 64 + mi * 16 + q * 4 + j;
        int col = wc * 64 + ni * 16 + m16;
        Cg[(size_t)row * DIM + col] = f2bf(acc[mi][ni][j]);
      }
    }
}

// ---------------- per-node attention + aggregation (one wave per node) ----------------
template<int H, bool ELU, bool OUT32>
__global__ void agg_kernel(const unsigned short* __restrict__ xr,
                           const float* __restrict__ qn, const float* __restrict__ kn,
                           const int* __restrict__ offs, const int* __restrict__ payload,
                           const void* __restrict__ bias,
                           void* __restrict__ outp,
                           const int* __restrict__ flags, int nN, int E){
  int is32 = flags[0];
  int wid  = (blockIdx.x * blockDim.x + threadIdx.x) >> 6;
  int lane = threadIdx.x & 63;
  int n = wid;
  int rs = offs[n], re = offs[n + 1];
  rs = max(rs, 0); re = min(re, E);
  const int myh = (H == 1) ? 0 : (lane >> 4);   // OUTC=192: lane*12/192 = lane/16

  float m_run[H], z_run[H], acc[12];
#pragma unroll
  for (int h = 0; h < H; ++h){ m_run[h] = -__builtin_inff(); z_run[h] = 0.f; }
#pragma unroll
  for (int i = 0; i < 12; ++i) acc[i] = 0.f;

  auto rowp = [&](int p) -> const uint2* {
    int et = p >> 16, src = p & 0xffff;
    return (const uint2*)(xr + ((size_t)et * nN + src) * DIM + lane * 12);
  };

  for (int base = rs; base < re; base += 64){
    int dc = min(64, re - base);
    int pay = 0;
    float al[H];
#pragma unroll
    for (int h = 0; h < H; ++h) al[h] = -__builtin_inff();
    if (lane < dc){
      pay = payload[base + lane];
      int et = pay >> 16, src = pay & 0xffff;
      if (H == 4){
        f32x4 qv = *(const f32x4*)(qn + ((size_t)et * nN + n)   * H);
        f32x4 kv = *(const f32x4*)(kn + ((size_t)et * nN + src) * H);
#pragma unroll
        for (int h = 0; h < H; ++h){
          float a = qv[h & 3] + kv[h & 3];
          al[h] = (a > 0.f) ? a : 0.2f * a;
        }
      } else {
        float a = qn[(size_t)pay * 0 + (size_t)et * nN + n] + kn[(size_t)et * nN + src];
        al[0] = (a > 0.f) ? a : 0.2f * a;
      }
    }
    // online-softmax chunk update
    float scs[H], wgt[H];
#pragma unroll
    for (int h = 0; h < H; ++h){
      float v = al[h];
      for (int off = 32; off; off >>= 1) v = fmaxf(v, __shfl_xor(v, off));
      float nm = fmaxf(m_run[h], v);
      scs[h] = (m_run[h] == -__builtin_inff()) ? 0.f : expf(m_run[h] - nm);
      m_run[h] = nm;
      wgt[h] = (lane < dc) ? expf(al[h] - nm) : 0.f;
      float s = wgt[h];
      for (int off = 32; off; off >>= 1) s += __shfl_xor(s, off);
      z_run[h] = z_run[h] * scs[h] + s;
    }
    float msc = sel<H>(scs, myh);
#pragma unroll
    for (int i = 0; i < 12; ++i) acc[i] *= msc;

    // 1-deep pipelined gather-accumulate
    int pj = __shfl(pay, 0);
    float wj;
    {
      float wsh[H];
#pragma unroll
      for (int h = 0; h < H; ++h) wsh[h] = __shfl(wgt[h], 0);
      wj = sel<H>(wsh, myh);
    }
    const uint2* rp = rowp(pj);
    uint2 c0 = rp[0], c1 = rp[1], c2 = rp[2];
    for (int j = 0; j < dc; ++j){
      uint2 n0 = {0,0}, n1 = {0,0}, n2 = {0,0};
      float wn = 0.f;
      if (j + 1 < dc){
        int pn = __shfl(pay, j + 1);
        float wsh[H];
#pragma unroll
        for (int h = 0; h < H; ++h) wsh[h] = __shfl(wgt[h], j + 1);
        wn = sel<H>(wsh, myh);
        const uint2* rn = rowp(pn);
        n0 = rn[0]; n1 = rn[1]; n2 = rn[2];
      }
      acc[0]  += wj * bfl(c0.x); acc[1]  += wj * bfh(c0.x);
      acc[2]  += wj * bfl(c0.y); acc[3]  += wj * bfh(c0.y);
      acc[4]  += wj * bfl(c1.x); acc[5]  += wj * bfh(c1.x);
      acc[6]  += wj * bfl(c1.y); acc[7]  += wj * bfh(c1.y);
      acc[8]  += wj * bfl(c2.x); acc[9]  += wj * bfh(c2.x);
      acc[10] += wj * bfl(c2.y); acc[11] += wj * bfh(c2.y);
      c0 = n0; c1 = n1; c2 = n2; wj = wn;
    }
  }

  float inv = 1.0f / (sel<H>(z_run, myh) + 1e-16f);
  float o[12];
#pragma unroll
  for (int i = 0; i < 12; ++i){
    float v = acc[i] * inv + ldf(bias, (size_t)lane * 12 + i, is32);
    if (ELU) v = (v > 0.f) ? v : (expf(v) - 1.f);
    o[i] = v;
  }
  if (OUT32 && is32){
    float* op = (float*)outp + (size_t)n * DIM + lane * 12;
    float4 f0 = {o[0], o[1], o[2],  o[3]};
    float4 f1 = {o[4], o[5], o[6],  o[7]};
    float4 f2 = {o[8], o[9], o[10], o[11]};
    ((float4*)op)[0] = f0; ((float4*)op)[1] = f1; ((float4*)op)[2] = f2;
  } else {
    uint2* op = (uint2*)((unsigned short*)outp + (size_t)n * DIM + lane * 12);
    uint2 s0, s1, s2;
    s0.x = pck(o[0], o[1]);  s0.y = pck(o[2], o[3]);
    s1.x = pck(o[4], o[5]);  s1.y = pck(o[6], o[7]);
    s2.x = pck(o[8], o[9]);  s2.y = pck(o[10], o[11]);
    op[0] = s0; op[1] = s1; op[2] = s2;
  }
}

// ---------------- launcher ----------------
extern "C" void kernel_launch(void* const* d_in, const int* in_sizes, int n_in,
                              void* d_out, int out_size, void* d_ws, size_t ws_size,
                              hipStream_t stream){
  const void* x   = d_in[0];
  const void* ei  = d_in[1];
  const void* ety = d_in[2];
  const void* W1  = d_in[3];
  const void* q1  = d_in[4];
  const void* k1  = d_in[5];
  const void* b1  = d_in[6];
  const void* W2  = d_in[7];
  const void* q2  = d_in[8];
  const void* k2  = d_in[9];
  const void* b2  = d_in[10];

  int nN = in_sizes[0] / DIM;   // 32768
  int E  = in_sizes[2];         // 160000

  char* ws = (char*)d_ws;
  size_t off = 0;
  auto alloc = [&](size_t bytes) -> void* {
    void* p = ws + off;
    off += (bytes + 255) & ~(size_t)255;
    return p;
  };
  unsigned short* xr  = (unsigned short*)alloc((size_t)NREL * nN * DIM * 2);
  unsigned short* xb  = (unsigned short*)alloc((size_t)nN * DIM * 2);
  unsigned short* h   = (unsigned short*)alloc((size_t)nN * DIM * 2);
  unsigned short* Wt  = (unsigned short*)alloc((size_t)NREL * DIM * DIM * 2);
  float* Wq  = (float*)alloc((size_t)NREL * DIM * 4 * 4);
  float* Wk  = (float*)alloc((size_t)NREL * DIM * 4 * 4);
  float* qn  = (float*)alloc((size_t)NREL * nN * 4 * 4);
  float* kn  = (float*)alloc((size_t)NREL * nN * 4 * 4);
  int* offs    = (int*)alloc((size_t)(nN + 1) * 4);
  int* cursor  = (int*)alloc((size_t)nN * 4);
  int* counts  = (int*)alloc((size_t)nN * 4);
  int* payload = (int*)alloc((size_t)E * 4);
  int* flags   = (int*)alloc(16);

  detect_kernel<<<1, 256, 0, stream>>>((const unsigned short*)x, (const unsigned*)ei,
                                       (const unsigned*)ety, flags);
  convert_x<<<(nN * DIM / 4 + 255) / 256, 256, 0, stream>>>(x, xb, flags, nN * DIM / 4);

  hipMemsetAsync(counts, 0, (size_t)nN * 4, stream);
  hist_kernel<<<(E + 255) / 256, 256, 0, stream>>>(ei, counts, flags, E);
  scan_kernel<<<1, 1024, 0, stream>>>(counts, offs, cursor, nN);
  scatter_kernel<<<(E + 255) / 256, 256, 0, stream>>>(ei, ety, cursor, payload, flags, E);

  dim3 tg(DIM / 32, DIM / 32, NREL), tb(32, 8);
  dim3 gg((DIM / 128) * NREL, nN / 128);

  // ---- layer 1 (H=4, ELU) ----
  transpose_w<<<tg, tb, 0, stream>>>(W1, Wt, flags);
  wqk_kernel<4><<<(NREL * DIM) / 4, 256, 0, stream>>>(W1, q1, k1, Wq, Wk, flags);
  qnkn_kernel<4><<<nN / 4, 256, 0, stream>>>(xb, Wq, Wk, qn, kn, nN);
  gemm_bf16<<<gg, 256, 0, stream>>>(xb, Wt, xr, nN);
  agg_kernel<4, true, false><<<nN / 4, 256, 0, stream>>>(xr, qn, kn, offs, payload, b1, h,
                                                         flags, nN, E);

  // ---- layer 2 (H=1, no activation) ----
  transpose_w<<<tg, tb, 0, stream>>>(W2, Wt, flags);
  wqk_kernel<1><<<(NREL * DIM) / 4, 256, 0, stream>>>(W2, q2, k2, Wq, Wk, flags);
  qnkn_kernel<1><<<nN / 4, 256, 0, stream>>>(h, Wq, Wk, qn, kn, nN);
  gemm_bf16<<<gg, 256, 0, stream>>>(h, Wt, xr, nN);
  agg_kernel<1, false, true><<<nN / 4, 256, 0, stream>>>(xr, qn, kn, offs, payload, b2,
                                                         d_out, flags, nN, E);
}

// Round 4
// 680.761 us; speedup vs baseline: 1.2348x; 1.2348x over previous
//
#include <hip/hip_runtime.h>

// RGAT encoder, 2 layers. N=32768, E=160000, DIM=768, R=3, heads 4 then 1.
// Round 4 (from 840 us): agg was latency-bound (Occ 17%, MfmaUtil 0, HBM 16%,
// 450k LDS conflicts from inner-loop shuffles). Changes:
//  - agg: chunk payload+weights staged in per-wave LDS (5KB), inner loop
//    gathers 4 edges/step (12 loads in flight) with no cross-lane ops
//  - qnkn: skinny MFMA GEMM (X @ Wqk[768x32], B pre-packed in fragment order)
//    replaces VALU version that re-read 147KB of weights per wave
//  - gemm: XCD-aware 1-D swizzle (i&7 = XCD, bm range per XCD, bnr fastest)

#define DIM   768
#define NREL  3

typedef __bf16 bf16x8 __attribute__((ext_vector_type(8)));
typedef float  f32x4  __attribute__((ext_vector_type(4)));
typedef unsigned short us4 __attribute__((ext_vector_type(4)));
typedef unsigned short us8 __attribute__((ext_vector_type(8)));

// ---------------- helpers ----------------
__device__ __forceinline__ float bfs(unsigned short u){
  union { unsigned u; float f; } v; v.u = ((unsigned)u) << 16; return v.f;
}
__device__ __forceinline__ float bfl(unsigned x){
  union { unsigned u; float f; } v; v.u = x << 16; return v.f;
}
__device__ __forceinline__ float bfh(unsigned x){
  union { unsigned u; float f; } v; v.u = x & 0xffff0000u; return v.f;
}
__device__ __forceinline__ unsigned short f2bf(float f){   // RNE
  union { float f; unsigned u; } v; v.f = f;
  unsigned r = v.u + 0x7fffu + ((v.u >> 16) & 1u);
  return (unsigned short)(r >> 16);
}
__device__ __forceinline__ unsigned pck(float a, float b){
  return (unsigned)f2bf(a) | ((unsigned)f2bf(b) << 16);
}
__device__ __forceinline__ float ldf(const void* p, size_t i, int is32){
  return is32 ? ((const float*)p)[i] : bfs(((const unsigned short*)p)[i]);
}
__device__ __forceinline__ int ldi(const void* p, size_t i, int is64){
  return is64 ? ((const int*)p)[2 * i] : ((const int*)p)[i];
}

typedef __attribute__((address_space(1))) void gvoid_t;
typedef __attribute__((address_space(3))) void lvoid_t;
__device__ __forceinline__ void gload16(const void* g, void* l){
  __builtin_amdgcn_global_load_lds((gvoid_t*)g, (lvoid_t*)l, 16, 0, 0);
}

template<int H>
__device__ __forceinline__ float sel(const float (&a)[H], int h){
  float v = a[0];
#pragma unroll
  for (int i = 1; i < H; ++i) v = (h == i) ? a[i] : v;
  return v;
}

// ---------------- dtype detection ----------------
__global__ void detect_kernel(const unsigned short* __restrict__ xu,
                              const unsigned* __restrict__ eiu,
                              const unsigned* __restrict__ etyu,
                              int* __restrict__ flags){
  __shared__ int s_weird, s_ei, s_ety;
  int t = threadIdx.x;
  if (t == 0){ s_weird = 0; s_ei = 0; s_ety = 0; }
  __syncthreads();
  unsigned short u = xu[2 * t];
  int ex = (u >> 7) & 0xff;
  if (ex >= 0xF0 || ex <= 0x40) atomicAdd(&s_weird, 1);
  if (t < 128){
    if (eiu[2 * t + 1]  != 0) atomicAdd(&s_ei, 1);
    if (etyu[2 * t + 1] != 0) atomicAdd(&s_ety, 1);
  }
  __syncthreads();
  if (t == 0){
    flags[0] = (s_weird > 16) ? 1 : 0;
    flags[1] = (s_ei  == 0) ? 1 : 0;
    flags[2] = (s_ety == 0) ? 1 : 0;
  }
}

// ---------------- x -> internal bf16 ----------------
__global__ void convert_x(const void* __restrict__ xin, unsigned short* __restrict__ xb,
                          const int* __restrict__ flags, int n4){
  int i = blockIdx.x * blockDim.x + threadIdx.x;
  if (i >= n4) return;
  if (flags[0]){
    float4 v = ((const float4*)xin)[i];
    us4 o; o.x = f2bf(v.x); o.y = f2bf(v.y); o.z = f2bf(v.z); o.w = f2bf(v.w);
    ((us4*)xb)[i] = o;
  } else {
    ((us4*)xb)[i] = ((const us4*)xin)[i];
  }
}

// ---------------- CSR build ----------------
__global__ void hist_kernel(const void* __restrict__ ei, int* __restrict__ counts,
                            const int* __restrict__ flags, int E){
  int e = blockIdx.x * blockDim.x + threadIdx.x;
  if (e < E) atomicAdd(&counts[ldi(ei, (size_t)E + e, flags[1])], 1);
}

__global__ void scan_kernel(const int* __restrict__ counts, int* __restrict__ offs,
                            int* __restrict__ cursor, int n){
  __shared__ int s[1024];
  int tid = threadIdx.x;
  int base = tid * 32;
  int loc[32];
  int run = 0;
#pragma unroll
  for (int i = 0; i < 32; ++i){ loc[i] = run; run += counts[base + i]; }
  s[tid] = run;
  __syncthreads();
  for (int off = 1; off < 1024; off <<= 1){
    int add = (tid >= off) ? s[tid - off] : 0;
    __syncthreads();
    s[tid] += add;
    __syncthreads();
  }
  int ex = (tid == 0) ? 0 : s[tid - 1];
#pragma unroll
  for (int i = 0; i < 32; ++i){
    int o = ex + loc[i];
    offs[base + i]   = o;
    cursor[base + i] = o;
  }
  if (tid == 1023) offs[n] = s[1023];
}

__global__ void scatter_kernel(const void* __restrict__ ei, const void* __restrict__ ety,
                               int* __restrict__ cursor, int* __restrict__ payload,
                               const int* __restrict__ flags, int E){
  int e = blockIdx.x * blockDim.x + threadIdx.x;
  if (e < E){
    int dst = ldi(ei, (size_t)E + e, flags[1]);
    int src = ldi(ei, (size_t)e,     flags[1]);
    int et  = ldi(ety, (size_t)e,    flags[2]);
    int pos = atomicAdd(&cursor[dst], 1);
    payload[pos] = (et << 16) | src;
  }
}

// ---------------- W transpose+convert ----------------
__global__ void transpose_w(const void* __restrict__ W, unsigned short* __restrict__ Wt,
                            const int* __restrict__ flags){
  __shared__ unsigned short t[32][33];
  int is32 = flags[0];
  int r = blockIdx.z;
  size_t Wb = (size_t)r * DIM * DIM;
  unsigned short* Wd = Wt + (size_t)r * DIM * DIM;
  int tx = threadIdx.x, ty = threadIdx.y;
  int x  = blockIdx.x * 32 + tx;
  int y0 = blockIdx.y * 32;
#pragma unroll
  for (int i = 0; i < 32; i += 8)
    t[ty + i][tx] = f2bf(ldf(W, Wb + (size_t)(y0 + ty + i) * DIM + x, is32));
  __syncthreads();
  int x2 = blockIdx.y * 32 + tx;
  int y2 = blockIdx.x * 32;
#pragma unroll
  for (int i = 0; i < 32; i += 8) Wd[(size_t)(y2 + ty + i) * DIM + x2] = t[tx][ty + i];
}

// ---------------- Wqkb[d][32] (bf16) = [W@q | W@k] per relation ----------------
// col = r*8 + isK*4 + h  (cols 24..31 pad; zeroed by memset before launch)
template<int H>
__global__ void wqk_kernel(const void* __restrict__ W,
                           const void* __restrict__ q, const void* __restrict__ k,
                           unsigned short* __restrict__ Wqkb,
                           const int* __restrict__ flags){
  int is32 = flags[0];
  int wid  = (blockIdx.x * blockDim.x + threadIdx.x) >> 6;
  int lane = threadIdx.x & 63;
  int r = wid / DIM, d = wid % DIM;
  size_t Wrow = ((size_t)r * DIM + d) * DIM;
  float aq[H], ak[H];
#pragma unroll
  for (int h = 0; h < H; ++h){ aq[h] = 0.f; ak[h] = 0.f; }
#pragma unroll
  for (int j = 0; j < 12; ++j){
    int f = j * 64 + lane;
    float wv = ldf(W, Wrow + f, is32);
#pragma unroll
    for (int h = 0; h < H; ++h){
      aq[h] += wv * ldf(q, (size_t)f * H + h, is32);
      ak[h] += wv * ldf(k, (size_t)f * H + h, is32);
    }
  }
#pragma unroll
  for (int h = 0; h < H; ++h){
    for (int off = 32; off; off >>= 1){
      aq[h] += __shfl_xor(aq[h], off);
      ak[h] += __shfl_xor(ak[h], off);
    }
  }
  if (lane == 0){
#pragma unroll
    for (int h = 0; h < H; ++h){
      Wqkb[(size_t)d * 32 + r * 8 + h]     = f2bf(aq[h]);
      Wqkb[(size_t)d * 32 + r * 8 + 4 + h] = f2bf(ak[h]);
    }
  }
}

// ---------------- pack Wqkb into MFMA B-fragment order ----------------
// Bpk[t][nt][lane] = 8 bf16: Wqkb[t*32 + (lane>>4)*8 + j][nt*16 + (lane&15)]
__global__ void pack_b(const unsigned short* __restrict__ Wqkb, unsigned short* __restrict__ Bpk){
  int i = blockIdx.x * 256 + threadIdx.x;   // 24*2*64 = 3072
  if (i >= 3072) return;
  int lane = i & 63, nt = (i >> 6) & 1, t = i >> 7;
  int kb = t * 32 + (lane >> 4) * 8;
  int col = nt * 16 + (lane & 15);
  us8 v;
#pragma unroll
  for (int j = 0; j < 8; ++j) v[j] = Wqkb[(size_t)(kb + j) * 32 + col];
  ((us8*)Bpk)[i] = v;
}

// ---------------- qn/kn via skinny MFMA: [N,768]@[768,32] ----------------
// output layout qn[r][n][4], kn[r][n][4] fp32 (H=4 uses all, H=1 uses h=0)
__global__ void __launch_bounds__(256)
qnkn_mfma(const unsigned short* __restrict__ X, const unsigned short* __restrict__ Bpk,
          float* __restrict__ qn, float* __restrict__ kn, int nN){
  int wv = threadIdx.x >> 6, lane = threadIdx.x & 63;
  int row0 = (blockIdx.x * 4 + wv) * 16;
  int ar = lane & 15, quad = lane >> 4;
  const unsigned short* Arow = X + (size_t)(row0 + ar) * DIM + quad * 8;
  const bf16x8* Bp = (const bf16x8*)Bpk;
  f32x4 acc0 = {0.f,0.f,0.f,0.f}, acc1 = {0.f,0.f,0.f,0.f};
#pragma unroll
  for (int t = 0; t < 24; ++t){
    bf16x8 a  = *(const bf16x8*)(Arow + t * 32);
    bf16x8 b0 = Bp[(t * 2 + 0) * 64 + lane];
    bf16x8 b1 = Bp[(t * 2 + 1) * 64 + lane];
    acc0 = __builtin_amdgcn_mfma_f32_16x16x32_bf16(a, b0, acc0, 0, 0, 0);
    acc1 = __builtin_amdgcn_mfma_f32_16x16x32_bf16(a, b1, acc1, 0, 0, 0);
  }
#pragma unroll
  for (int nt = 0; nt < 2; ++nt){
    int col = nt * 16 + (lane & 15);
    if (col < 24){
      int r = col >> 3, isK = (col >> 2) & 1, h = col & 3;
      float* bp = isK ? kn : qn;
      f32x4 a = nt ? acc1 : acc0;
#pragma unroll
      for (int j = 0; j < 4; ++j){
        int row = row0 + quad * 4 + j;
        bp[((size_t)r * nN + row) * 4 + h] = a[j];
      }
    }
  }
}

// ---------------- MFMA GEMM: C[r] = A @ W[r], XCD-aware swizzle ----------------
// 1-D grid 4608: xcd = i&7 owns bm in [xcd*32, xcd*32+32); bnr fastest so the
// A-tile stays hot in that XCD's L2 across all 18 (bn,r) blocks.
__global__ void __launch_bounds__(256)
gemm_bf16(const unsigned short* __restrict__ A,
          const unsigned short* __restrict__ Bt,
          unsigned short* __restrict__ C, int M){
  __shared__ __align__(16) unsigned char lA[128 * 64 * 2];
  __shared__ __align__(16) unsigned char lB[128 * 64 * 2];
  const int K = DIM;
  int i = blockIdx.x;
  int xcd = i & 7, s = i >> 3;
  int bnr = s % 18;
  int bm  = xcd * 32 + s / 18;
  int bn = bnr % 6, r = bnr / 6;
  int tid = threadIdx.x;
  int w = tid >> 6, lane = tid & 63;
  int wr = w >> 1, wc = w & 1;
  int q = lane >> 4, m16 = lane & 15;
  int sr8 = lane >> 3, kc = lane & 7;

  const unsigned short* Ag = A  + (size_t)bm * 128 * K;
  const unsigned short* Bg = Bt + ((size_t)r * DIM + (size_t)bn * 128) * K;

  f32x4 acc[4][4];
#pragma unroll
  for (int a = 0; a < 4; ++a)
#pragma unroll
    for (int b = 0; b < 4; ++b) acc[a][b] = (f32x4){0.f, 0.f, 0.f, 0.f};

  for (int k0 = 0; k0 < K; k0 += 64){
#pragma unroll
    for (int it = 0; it < 4; ++it){
      int row = w * 32 + it * 8 + sr8;
      int cl  = kc ^ (row & 7);
      gload16(Ag + (size_t)row * K + k0 + cl * 8, &lA[(w * 32 + it * 8) * 128]);
      gload16(Bg + (size_t)row * K + k0 + cl * 8, &lB[(w * 32 + it * 8) * 128]);
    }
    __builtin_amdgcn_s_waitcnt(0);
    __syncthreads();
#pragma unroll
    for (int kk = 0; kk < 2; ++kk){
      bf16x8 af[4], bfr[4];
      int c = kk * 4 + q;
#pragma unroll
      for (int mi = 0; mi < 4; ++mi){
        int row = wr * 64 + mi * 16 + m16;
        af[mi] = *(const bf16x8*)&lA[row * 128 + ((c ^ (row & 7)) << 4)];
      }
#pragma unroll
      for (int ni = 0; ni < 4; ++ni){
        int row = wc * 64 + ni * 16 + m16;
        bfr[ni] = *(const bf16x8*)&lB[row * 128 + ((c ^ (row & 7)) << 4)];
      }
#pragma unroll
      for (int mi = 0; mi < 4; ++mi)
#pragma unroll
        for (int ni = 0; ni < 4; ++ni)
          acc[mi][ni] = __builtin_amdgcn_mfma_f32_16x16x32_bf16(af[mi], bfr[ni], acc[mi][ni], 0, 0, 0);
    }
    __syncthreads();
  }
  unsigned short* Cg = C + ((size_t)r * M + (size_t)bm * 128) * DIM + bn * 128;
#pragma unroll
  for (int mi = 0; mi < 4; ++mi)
#pragma unroll
    for (int ni = 0; ni < 4; ++ni){
#pragma unroll
      for (int j = 0; j < 4; ++j){
        int row = wr * 64 + mi * 16 + q * 4 + j;
        int col = wc * 64 + ni * 16 + m16;
        Cg[(size_t)row * DIM + col] = f2bf(acc[mi][ni][j]);
      }
    }
}

// ---------------- per-node attention + aggregation (one wave per node) ----------------
// Per-wave LDS for chunk payload/weights (no inner-loop shuffles); gathers
// batched 4-wide for MLP (12 independent loads in flight).
template<int H, bool ELU, bool OUT32>
__global__ void __launch_bounds__(256)
agg_kernel(const unsigned short* __restrict__ xr,
           const float* __restrict__ qn, const float* __restrict__ kn,
           const int* __restrict__ offs, const int* __restrict__ payload,
           const void* __restrict__ bias,
           void* __restrict__ outp,
           const int* __restrict__ flags, int nN, int E){
  const int WH = (H == 4) ? 4 : 1;
  __shared__ int   pay_s[4][64];
  __shared__ float w_s[4][64 * WH];
  int is32 = flags[0];
  int wv   = threadIdx.x >> 6;
  int lane = threadIdx.x & 63;
  int n = blockIdx.x * 4 + wv;
  int rs = offs[n], re = offs[n + 1];
  rs = max(rs, 0); re = min(re, E);
  const int myh = (H == 1) ? 0 : (lane >> 4);   // OUTC=192: lane*12/192 = lane/16

  float m_run[H], z_run[H], acc[12];
#pragma unroll
  for (int h = 0; h < H; ++h){ m_run[h] = -__builtin_inff(); z_run[h] = 0.f; }
#pragma unroll
  for (int i = 0; i < 12; ++i) acc[i] = 0.f;

  for (int base = rs; base < re; base += 64){
    int dc = min(64, re - base);
    int pay = 0;
    float al[H];
#pragma unroll
    for (int h = 0; h < H; ++h) al[h] = -__builtin_inff();
    if (lane < dc){
      pay = payload[base + lane];
      int et = pay >> 16, src = pay & 0xffff;
      if (H == 4){
        f32x4 qv = *(const f32x4*)(qn + ((size_t)et * nN + n)   * 4);
        f32x4 kv = *(const f32x4*)(kn + ((size_t)et * nN + src) * 4);
#pragma unroll
        for (int h = 0; h < H; ++h){
          float a = qv[h & 3] + kv[h & 3];
          al[h] = (a > 0.f) ? a : 0.2f * a;
        }
      } else {
        float a = qn[((size_t)et * nN + n) * 4] + kn[((size_t)et * nN + src) * 4];
        al[0] = (a > 0.f) ? a : 0.2f * a;
      }
    }
    // online-softmax chunk update
    float scs[H], wgt[H];
#pragma unroll
    for (int h = 0; h < H; ++h){
      float v = al[h];
      for (int off = 32; off; off >>= 1) v = fmaxf(v, __shfl_xor(v, off));
      float nm = fmaxf(m_run[h], v);
      scs[h] = (m_run[h] == -__builtin_inff()) ? 0.f : expf(m_run[h] - nm);
      m_run[h] = nm;
      wgt[h] = (lane < dc) ? expf(al[h] - nm) : 0.f;
      float s = wgt[h];
      for (int off = 32; off; off >>= 1) s += __shfl_xor(s, off);
      z_run[h] = z_run[h] * scs[h] + s;
    }
    float msc = sel<H>(scs, myh);
#pragma unroll
    for (int i = 0; i < 12; ++i) acc[i] *= msc;

    // stash chunk data in per-wave LDS (same-wave DS ops are in-order)
    if (lane < dc){
      pay_s[wv][lane] = pay;
#pragma unroll
      for (int h = 0; h < WH; ++h) w_s[wv][lane * WH + h] = wgt[h];
    }

    // batched gather-accumulate: 4 edges -> 12 loads in flight
    for (int j0 = 0; j0 < dc; j0 += 4){
      uint2 c[4][3];
      float w4[4];
#pragma unroll
      for (int u = 0; u < 4; ++u){
        int jc = j0 + u;
        int ok = jc < dc;
        int jl = ok ? jc : j0;
        int pj = pay_s[wv][jl];
        float ww = w_s[wv][jl * WH + ((H == 1) ? 0 : myh)];
        w4[u] = ok ? ww : 0.f;
        int et = pj >> 16, src = pj & 0xffff;
        const uint2* rp = (const uint2*)(xr + ((size_t)et * nN + src) * DIM + lane * 12);
        c[u][0] = rp[0]; c[u][1] = rp[1]; c[u][2] = rp[2];
      }
#pragma unroll
      for (int u = 0; u < 4; ++u){
        float wj = w4[u];
        acc[0]  += wj * bfl(c[u][0].x); acc[1]  += wj * bfh(c[u][0].x);
        acc[2]  += wj * bfl(c[u][0].y); acc[3]  += wj * bfh(c[u][0].y);
        acc[4]  += wj * bfl(c[u][1].x); acc[5]  += wj * bfh(c[u][1].x);
        acc[6]  += wj * bfl(c[u][1].y); acc[7]  += wj * bfh(c[u][1].y);
        acc[8]  += wj * bfl(c[u][2].x); acc[9]  += wj * bfh(c[u][2].x);
        acc[10] += wj * bfl(c[u][2].y); acc[11] += wj * bfh(c[u][2].y);
      }
    }
  }

  float inv = 1.0f / (sel<H>(z_run, myh) + 1e-16f);
  float o[12];
#pragma unroll
  for (int i = 0; i < 12; ++i){
    float v = acc[i] * inv + ldf(bias, (size_t)lane * 12 + i, is32);
    if (ELU) v = (v > 0.f) ? v : (expf(v) - 1.f);
    o[i] = v;
  }
  if (OUT32 && is32){
    float* op = (float*)outp + (size_t)n * DIM + lane * 12;
    float4 f0 = {o[0], o[1], o[2],  o[3]};
    float4 f1 = {o[4], o[5], o[6],  o[7]};
    float4 f2 = {o[8], o[9], o[10], o[11]};
    ((float4*)op)[0] = f0; ((float4*)op)[1] = f1; ((float4*)op)[2] = f2;
  } else {
    uint2* op = (uint2*)((unsigned short*)outp + (size_t)n * DIM + lane * 12);
    uint2 s0, s1, s2;
    s0.x = pck(o[0], o[1]);  s0.y = pck(o[2], o[3]);
    s1.x = pck(o[4], o[5]);  s1.y = pck(o[6], o[7]);
    s2.x = pck(o[8], o[9]);  s2.y = pck(o[10], o[11]);
    op[0] = s0; op[1] = s1; op[2] = s2;
  }
}

// ---------------- launcher ----------------
extern "C" void kernel_launch(void* const* d_in, const int* in_sizes, int n_in,
                              void* d_out, int out_size, void* d_ws, size_t ws_size,
                              hipStream_t stream){
  const void* x   = d_in[0];
  const void* ei  = d_in[1];
  const void* ety = d_in[2];
  const void* W1  = d_in[3];
  const void* q1  = d_in[4];
  const void* k1  = d_in[5];
  const void* b1  = d_in[6];
  const void* W2  = d_in[7];
  const void* q2  = d_in[8];
  const void* k2  = d_in[9];
  const void* b2  = d_in[10];

  int nN = in_sizes[0] / DIM;   // 32768
  int E  = in_sizes[2];         // 160000

  char* ws = (char*)d_ws;
  size_t off = 0;
  auto alloc = [&](size_t bytes) -> void* {
    void* p = ws + off;
    off += (bytes + 255) & ~(size_t)255;
    return p;
  };
  unsigned short* xr   = (unsigned short*)alloc((size_t)NREL * nN * DIM * 2);
  unsigned short* xb   = (unsigned short*)alloc((size_t)nN * DIM * 2);
  unsigned short* h    = (unsigned short*)alloc((size_t)nN * DIM * 2);
  unsigned short* Wt   = (unsigned short*)alloc((size_t)NREL * DIM * DIM * 2);
  unsigned short* Wqkb = (unsigned short*)alloc((size_t)DIM * 32 * 2);
  unsigned short* Bpk  = (unsigned short*)alloc((size_t)3072 * 16);
  float* qn  = (float*)alloc((size_t)NREL * nN * 4 * 4);
  float* kn  = (float*)alloc((size_t)NREL * nN * 4 * 4);
  int* offs    = (int*)alloc((size_t)(nN + 1) * 4);
  int* cursor  = (int*)alloc((size_t)nN * 4);
  int* counts  = (int*)alloc((size_t)nN * 4);
  int* payload = (int*)alloc((size_t)E * 4);
  int* flags   = (int*)alloc(16);

  detect_kernel<<<1, 256, 0, stream>>>((const unsigned short*)x, (const unsigned*)ei,
                                       (const unsigned*)ety, flags);
  convert_x<<<(nN * DIM / 4 + 255) / 256, 256, 0, stream>>>(x, xb, flags, nN * DIM / 4);

  hipMemsetAsync(counts, 0, (size_t)nN * 4, stream);
  hist_kernel<<<(E + 255) / 256, 256, 0, stream>>>(ei, counts, flags, E);
  scan_kernel<<<1, 1024, 0, stream>>>(counts, offs, cursor, nN);
  scatter_kernel<<<(E + 255) / 256, 256, 0, stream>>>(ei, ety, cursor, payload, flags, E);

  dim3 tg(DIM / 32, DIM / 32, NREL), tb(32, 8);
  int gemm_blocks = 8 * (18 * 32);   // 4608

  // ---- layer 1 (H=4, ELU) ----
  transpose_w<<<tg, tb, 0, stream>>>(W1, Wt, flags);
  hipMemsetAsync(Wqkb, 0, (size_t)DIM * 32 * 2, stream);
  wqk_kernel<4><<<(NREL * DIM) / 4, 256, 0, stream>>>(W1, q1, k1, Wqkb, flags);
  pack_b<<<12, 256, 0, stream>>>(Wqkb, Bpk);
  qnkn_mfma<<<nN / 64, 256, 0, stream>>>(xb, Bpk, qn, kn, nN);
  gemm_bf16<<<gemm_blocks, 256, 0, stream>>>(xb, Wt, xr, nN);
  agg_kernel<4, true, false><<<nN / 4, 256, 0, stream>>>(xr, qn, kn, offs, payload, b1, h,
                                                         flags, nN, E);

  // ---- layer 2 (H=1, no activation) ----
  transpose_w<<<tg, tb, 0, stream>>>(W2, Wt, flags);
  hipMemsetAsync(Wqkb, 0, (size_t)DIM * 32 * 2, stream);
  wqk_kernel<1><<<(NREL * DIM) / 4, 256, 0, stream>>>(W2, q2, k2, Wqkb, flags);
  pack_b<<<12, 256, 0, stream>>>(Wqkb, Bpk);
  qnkn_mfma<<<nN / 64, 256, 0, stream>>>(h, Bpk, qn, kn, nN);
  gemm_bf16<<<gemm_blocks, 256, 0, stream>>>(h, Wt, xr, nN);
  agg_kernel<1, false, true><<<nN / 4, 256, 0, stream>>>(xr, qn, kn, offs, payload, b2,
                                                         d_out, flags, nN, E);
}